// Round 6
// baseline (436.232 us; speedup 1.0000x reference)
//
#include <hip/hip_runtime.h>

// Problem constants (from reference): x [T, B, C, H, W] = [5, 32, 128, 32, 32]
constexpr int T    = 5;
constexpr int Bn   = 32;
constexpr int C    = 128;
constexpr int HW   = 32 * 32;              // 1024
constexpr int NPT4 = Bn * C * HW / 4;      // float4s per timestep = 1,048,576

constexpr int THREADS = 1024;              // 16 waves
constexpr int WAVES   = THREADS / 64;
constexpr int BLOCKS  = 2 * C;             // 256 blocks -> ALL 256 CUs active
constexpr int F4T     = 4;                 // float4s per thread per timestep
                                           // (16 batches * 256 f4) / 1024 thr

// Write-once tagged exchange slots in d_ws: one u32 per (t, c, half).
//   value = (TAG(t) << 20) | spike_count,  count <= 16384 < 2^20.
// TAG(t) = 0x500 + t never equals the 0xAAA tag of the 0xAA poison, so NO
// zeroing pass is needed — single plain launch, no helper kernels (the
// R2-R4 failure path). Word atomicity: seeing TAG(t) implies count valid.
constexpr unsigned int TAG0 = 0x500u;
__device__ __forceinline__ unsigned int pack(int t, unsigned int cnt) {
  return ((TAG0 + (unsigned)t) << 20) | cnt;
}

// 256 blocks x 16 waves: capacity is 32 waves/CU so the whole grid is
// co-resident on 256 CUs — the pair-spin cannot deadlock without
// cooperative launch. launch_bounds(1024) caps VGPR at 128.
__global__ __launch_bounds__(THREADS)
void lif_kernel(const float* __restrict__ xe_g,
                const float* __restrict__ xi_g,
                const float* __restrict__ alpha_raw,
                const float* __restrict__ beta_raw,
                float* __restrict__ out,
                unsigned int* __restrict__ slots /* T*C*2 u32, poison-tolerant */) {
#pragma clang fp contract(off)
  const int blk  = blockIdx.x;
  const int c    = blk & (C - 1);   // channel
  const int half = blk >> 7;        // batch half; partner is blk ^ 128 (same XCD)
  const int tid  = threadIdx.x;
  const int wave = tid >> 6;
  const int lane = tid & 63;

  __shared__ unsigned int wsum[T - 1][WAVES];

  const float alpha = 4.0f / (1.0f + expf(-alpha_raw[0])); // 4*sigmoid
  const float beta  = 1.0f / (1.0f + expf(-beta_raw[0]));  // sigmoid

  // membrane state: 4 float4 = 16 VGPRs
  float mem[F4T][4];
#pragma unroll
  for (int k = 0; k < F4T; ++k)
#pragma unroll
    for (int j = 0; j < 4; ++j) mem[k][j] = 0.0f;

  float ema  = 0.17f; // EMA_INIT
  float inhw = 0.0f;

  const float4* xe4 = (const float4*)xe_g;
  const float4* xi4 = (const float4*)xi_g;
  float4*       o4  = (float4*)out;

  // block-local float4 index g = k*1024+tid in [0,4096):
  //   local batch = g>>8 (256 f4 per (b,c) tile), b = half*16 + local batch
  auto gidx = [&](int t, int k) -> size_t {
    const int g   = k * THREADS + tid;
    const int b   = half * (Bn / 2) + (g >> 8);
    const int off = g & 255;
    return (size_t)t * NPT4 + (size_t)(b * C + c) * 256 + off;
  };

  // prologue: t=0 inputs into registers
  float xe[F4T][4], xi[F4T][4];
#pragma unroll
  for (int k = 0; k < F4T; ++k) {
    const size_t idx = gidx(0, k);
    const float4 e4 = xe4[idx];
    const float4 i4 = xi4[idx];
    xe[k][0] = e4.x; xe[k][1] = e4.y; xe[k][2] = e4.z; xe[k][3] = e4.w;
    xi[k][0] = i4.x; xi[k][1] = i4.y; xi[k][2] = i4.z; xi[k][3] = i4.w;
  }

  for (int t = 0; t < T; ++t) {
    unsigned int local = 0;
#pragma unroll
    for (int k = 0; k < F4T; ++k) {
      const size_t idx = gidx(t, k);
      float sv[4];
#pragma unroll
      for (int j = 0; j < 4; ++j) {
        // identical arithmetic to R5 (absmax exactly 0.0): IEEE divide,
        // literal python op order, contract off
        const float e_in = xe[k][j] / (1.0f + alpha * xi[k][j]);
        const float a = 0.5f * mem[k][j];
        const float bb = a + e_in;
        const float d = (beta * xi[k][j]) * (1.0f - inhw);
        const float m = bb - d;
        const float x = m - 0.5f;            // mem - V_TH
        const float s = (x >= 0.0f) ? 1.0f : 0.0f;
        local += (x >= 0.0f) ? 1u : 0u;
        mem[k][j] = m - 0.5f * s;            // soft reset
        sv[j] = s;
      }
      float4 s4;
      s4.x = sv[0]; s4.y = sv[1]; s4.z = sv[2]; s4.w = sv[3];
      o4[idx] = s4;
    }

    if (t == T - 1) break; // last ema/inhw update is never read

    // prefetch t+1 inputs BEFORE publish/spin so exchange latency hides
#pragma unroll
    for (int k = 0; k < F4T; ++k) {
      const size_t idx = gidx(t + 1, k);
      const float4 e4 = xe4[idx];
      const float4 i4 = xi4[idx];
      xe[k][0] = e4.x; xe[k][1] = e4.y; xe[k][2] = e4.z; xe[k][3] = e4.w;
      xi[k][0] = i4.x; xi[k][1] = i4.y; xi[k][2] = i4.z; xi[k][3] = i4.w;
    }

    // block-local reduction (wave shuffle -> LDS -> broadcast sum)
#pragma unroll
    for (int off = 32; off > 0; off >>= 1) local += __shfl_down(local, off);
    if (lane == 0) wsum[t][wave] = local;
    __syncthreads();
    unsigned int mine = 0;
#pragma unroll
    for (int w = 0; w < WAVES; ++w) mine += wsum[t][w];

    // pair exchange: publish my tagged count, spin for partner's tag
    const int sbase = (t * C + c) * 2;
    if (tid == 0)
      __hip_atomic_store(&slots[sbase + half], pack(t, mine),
                         __ATOMIC_RELEASE, __HIP_MEMORY_SCOPE_AGENT);
    unsigned int v;
    while (((v = __hip_atomic_load(&slots[sbase + (half ^ 1)], __ATOMIC_ACQUIRE,
                                   __HIP_MEMORY_SCOPE_AGENT)) >> 20) !=
           TAG0 + (unsigned)t)
      __builtin_amdgcn_s_sleep(2);
    const unsigned int total = mine + (v & 0xFFFFFu);

    const float mean_spike = (float)total * (1.0f / 32768.0f); // exact /2^15
    ema = 0.9f * ema + 0.1f * mean_spike;
    const float s_lo = 1.0f / (1.0f + expf(-(0.17f - ema)));  // sigmoid(LOWER-ema)
    const float s_hi = 1.0f / (1.0f + expf(-(ema - 0.23f)));  // sigmoid(ema-UPPER)
    inhw = 4.0f * (s_lo - s_hi);
  }
}

extern "C" void kernel_launch(void* const* d_in, const int* in_sizes, int n_in,
                              void* d_out, int out_size, void* d_ws, size_t ws_size,
                              hipStream_t stream) {
  const float* xe = (const float*)d_in[0];
  const float* xi = (const float*)d_in[1];
  const float* ar = (const float*)d_in[2];
  const float* br = (const float*)d_in[3];
  float* out = (float*)d_out;
  unsigned int* slots = (unsigned int*)d_ws; // T*C*2 = 1280 u32 = 5120 B

  // single plain launch; tagged write-once slots tolerate 0xAA poison
  lif_kernel<<<dim3(BLOCKS), dim3(THREADS), 0, stream>>>(xe, xi, ar, br, out, slots);
}

// Round 7
// 243.117 us; speedup vs baseline: 1.7943x; 1.7943x over previous
//
#include <hip/hip_runtime.h>

// Problem constants (from reference): x [T, B, C, H, W] = [5, 32, 128, 32, 32]
constexpr int T    = 5;
constexpr int Bn   = 32;
constexpr int C    = 128;
constexpr int HW   = 32 * 32;              // 1024
constexpr int NPT4 = Bn * C * HW / 4;      // float4s per timestep = 1,048,576

constexpr int THREADS = 1024;              // 16 waves
constexpr int WAVES   = THREADS / 64;
constexpr int BLOCKS  = 2 * C;             // 256 blocks -> all 256 CUs
constexpr int K       = 8;                 // float4s per thread (full channel:
                                           // 8192 f4 / 1024 thr)

// REDUNDANT-PAIR SCHEME (R6 post-mortem: every cross-block spin costs ~65us;
// R1 grid sync ~110us — inter-block sync is the enemy on this part).
// Blocks c and c+128 BOTH compute channel c's full recurrence (bit-identical
// fp -> identical integer spike counts -> identical ema/inhw), each WRITES
// only its half of the batch. Recompute replaces communication entirely:
// no sync, no workspace, single plain launch (the only launch path that has
// ever passed). The twin's loads dedupe in L2/L3: pair is on the same XCD
// ((c+128)%8==c%8) and one timestep's inputs (67 MB) fit in the 256 MB L3,
// so HBM fetch stays ~1x.
__global__ __launch_bounds__(THREADS)
void lif_kernel(const float* __restrict__ xe_g,
                const float* __restrict__ xi_g,
                const float* __restrict__ alpha_raw,
                const float* __restrict__ beta_raw,
                float* __restrict__ out) {
#pragma clang fp contract(off)
  const int blk  = blockIdx.x;
  const int c    = blk & (C - 1);   // channel (computed redundantly by 2 blocks)
  const int half = blk >> 7;        // which batch half this block WRITES
  const int tid  = threadIdx.x;
  const int wave = tid >> 6;
  const int lane = tid & 63;

  __shared__ unsigned int wsum[T - 1][WAVES];

  const float alpha = 4.0f / (1.0f + expf(-alpha_raw[0])); // 4*sigmoid
  const float beta  = 1.0f / (1.0f + expf(-beta_raw[0]));  // sigmoid

  // membrane state for ALL 32 owned elements of the channel: 8 f4 = 32 VGPRs
  float mem[K][4];
#pragma unroll
  for (int k = 0; k < K; ++k)
#pragma unroll
    for (int j = 0; j < 4; ++j) mem[k][j] = 0.0f;

  float ema  = 0.17f; // EMA_INIT
  float inhw = 0.0f;

  const float4* xe4 = (const float4*)xe_g;
  const float4* xi4 = (const float4*)xi_g;
  float4*       o4  = (float4*)out;

  // f4 index for (t,k): g = k*1024 + tid in [0,8192); batch b = g>>8
  // (256 f4 per (b,c) tile). Consecutive tid -> consecutive addresses.
  auto gidx = [&](int t, int k) -> size_t {
    const int b   = k * (THREADS / 256) + (tid >> 8);
    const int off = tid & 255;
    return (size_t)t * NPT4 + (size_t)(b * C + c) * 256 + off;
  };

  for (int t = 0; t < T; ++t) {
    // 1) load the ENTIRE timestep's inputs into registers first: 16 f4 loads
    //    in flight per thread (R5 kept only ~2-4 outstanding -> 63% ceiling)
    float4 e4[K], i4[K];
#pragma unroll
    for (int k = 0; k < K; ++k) {
      const size_t idx = gidx(t, k);
      e4[k] = xe4[idx];
      i4[k] = xi4[idx];
    }

    // 2) compute all 32 elements; count spikes over the FULL channel
    unsigned int local = 0;
#pragma unroll
    for (int k = 0; k < K; ++k) {
      const float xe[4] = {e4[k].x, e4[k].y, e4[k].z, e4[k].w};
      const float xi[4] = {i4[k].x, i4[k].y, i4[k].z, i4[k].w};
      float sv[4];
#pragma unroll
      for (int j = 0; j < 4; ++j) {
        // identical arithmetic to R5/R6 (absmax exactly 0.0): IEEE divide,
        // literal python op order, contract off
        const float e_in = xe[j] / (1.0f + alpha * xi[j]);
        const float a  = 0.5f * mem[k][j];
        const float bb = a + e_in;
        const float d  = (beta * xi[j]) * (1.0f - inhw);
        const float m  = bb - d;
        const float x  = m - 0.5f;           // mem - V_TH
        const float s  = (x >= 0.0f) ? 1.0f : 0.0f;
        local += (x >= 0.0f) ? 1u : 0u;
        mem[k][j] = m - 0.5f * s;            // soft reset
        sv[j] = s;
      }
      // 3) write ONLY my half of the batch: k>>2 == half  (b = k*4 + tid>>8,
      //    so k in [4*half, 4*half+4) covers b in [16*half, 16*half+16))
      if ((k >> 2) == half) {
        float4 s4;
        s4.x = sv[0]; s4.y = sv[1]; s4.z = sv[2]; s4.w = sv[3];
        o4[gidx(t, k)] = s4;
      }
    }

    if (t == T - 1) break; // last ema/inhw update is never read

    // block-LOCAL reduction only (wave shuffle -> LDS -> broadcast sum);
    // both partner blocks arrive at the same integer -> same ema/inhw
#pragma unroll
    for (int off = 32; off > 0; off >>= 1) local += __shfl_down(local, off);
    if (lane == 0) wsum[t][wave] = local;
    __syncthreads();
    unsigned int total = 0;
#pragma unroll
    for (int w = 0; w < WAVES; ++w) total += wsum[t][w];

    const float mean_spike = (float)total * (1.0f / 32768.0f); // exact /2^15
    ema = 0.9f * ema + 0.1f * mean_spike;
    const float s_lo = 1.0f / (1.0f + expf(-(0.17f - ema)));  // sigmoid(LOWER-ema)
    const float s_hi = 1.0f / (1.0f + expf(-(ema - 0.23f)));  // sigmoid(ema-UPPER)
    inhw = 4.0f * (s_lo - s_hi);
  }
}

extern "C" void kernel_launch(void* const* d_in, const int* in_sizes, int n_in,
                              void* d_out, int out_size, void* d_ws, size_t ws_size,
                              hipStream_t stream) {
  const float* xe = (const float*)d_in[0];
  const float* xi = (const float*)d_in[1];
  const float* ar = (const float*)d_in[2];
  const float* br = (const float*)d_in[3];
  float* out = (float*)d_out;

  // single plain launch: no workspace, no helper kernels, no inter-block sync
  lif_kernel<<<dim3(BLOCKS), dim3(THREADS), 0, stream>>>(xe, xi, ar, br, out);
}

// Round 8
// 227.051 us; speedup vs baseline: 1.9213x; 1.0708x over previous
//
#include <hip/hip_runtime.h>

// Problem: x [T, B, C, H, W] = [5, 32, 128, 32, 32] fp32, LIF scan.
// R7 post-mortem: redundant-pair saturates L2/L3 fabric (~15 TB/s) at 114us.
// R8: one plain kernel per timestep (kernel boundary = free device sync).
// Each element computed ONCE; mem state round-trips via d_ws (L3-resident);
// per-block integer spike partials carry the per-channel coupling.
constexpr int T    = 5;
constexpr int C    = 128;
constexpr int NPT4 = 32 * C * 1024 / 4;    // f4 per timestep = 1,048,576

// ---- streaming per-timestep kernel ----
constexpr int SBLOCKS  = 1024;
constexpr int STHREADS = 256;
constexpr int KT       = 4;                // (b,c) tiles per block (4096/1024)

// d_ws layout: [ partials u32[T][SBLOCKS] | mem float4[NPT4] ]
constexpr size_t PART_BYTES = (size_t)T * SBLOCKS * sizeof(unsigned int); // 20480
constexpr size_t WS_NEEDED  = PART_BYTES + (size_t)NPT4 * 16;             // ~16.8MB

__global__ __launch_bounds__(STHREADS)
void lif_step(const float4* __restrict__ xe4,
              const float4* __restrict__ xi4,
              const float* __restrict__ alpha_raw,
              const float* __restrict__ beta_raw,
              float4* __restrict__ out4,
              float4* __restrict__ memb,
              unsigned int* __restrict__ partials,
              int t) {
#pragma clang fp contract(off)
  const int blk = blockIdx.x;
  const int tid = threadIdx.x;
  const int c   = blk & (C - 1);  // tiles k*1024+blk are all channel blk%128

  // thread 0 reconstructs the ema chain from prior steps' partials (<=32 u32
  // loads); LDS-broadcast inhw. Bit-identical fp sequence to the R7 chain.
  __shared__ float s_inhw;
  if (tid == 0) {
    float inhw = 0.0f;
    if (t > 0) {
      float ema = 0.17f;                       // EMA_INIT
      for (int s = 0; s < t; ++s) {
        unsigned int tot = 0;
#pragma unroll
        for (int i = 0; i < 8; ++i) tot += partials[s * SBLOCKS + c + i * C];
        const float mean = (float)tot * (1.0f / 32768.0f);   // exact /2^15
        ema = 0.9f * ema + 0.1f * mean;
      }
      const float s_lo = 1.0f / (1.0f + expf(-(0.17f - ema))); // sig(LOWER-ema)
      const float s_hi = 1.0f / (1.0f + expf(-(ema - 0.23f))); // sig(ema-UPPER)
      inhw = 4.0f * (s_lo - s_hi);
    }
    s_inhw = inhw;
  }
  __syncthreads();
  const float inhw  = s_inhw;
  const float alpha = 4.0f / (1.0f + expf(-alpha_raw[0])); // 4*sigmoid
  const float beta  = 1.0f / (1.0f + expf(-beta_raw[0]));  // sigmoid

  unsigned int local = 0;
  const size_t tb = (size_t)t * NPT4;
#pragma unroll
  for (int k = 0; k < KT; ++k) {
    const size_t fi = (size_t)(k * SBLOCKS + blk) * 256 + tid; // f4 idx in step
    const float4 e4 = xe4[tb + fi];
    const float4 i4 = xi4[tb + fi];
    float4 m4 = {0.0f, 0.0f, 0.0f, 0.0f};
    if (t > 0) m4 = memb[fi];
    const float xe[4] = {e4.x, e4.y, e4.z, e4.w};
    const float xi[4] = {i4.x, i4.y, i4.z, i4.w};
    float mv[4] = {m4.x, m4.y, m4.z, m4.w};
    float sv[4];
#pragma unroll
    for (int j = 0; j < 4; ++j) {
      // identical arithmetic to R5/R7 (absmax exactly 0.0): IEEE divide,
      // literal python op order, contract off
      const float e_in = xe[j] / (1.0f + alpha * xi[j]);
      const float a  = 0.5f * mv[j];
      const float bb = a + e_in;
      const float d  = (beta * xi[j]) * (1.0f - inhw);
      const float m  = bb - d;
      const float x  = m - 0.5f;             // mem - V_TH
      const float s  = (x >= 0.0f) ? 1.0f : 0.0f;
      local += (x >= 0.0f) ? 1u : 0u;
      mv[j] = m - 0.5f * s;                  // soft reset
      sv[j] = s;
    }
    float4 s4; s4.x = sv[0]; s4.y = sv[1]; s4.z = sv[2]; s4.w = sv[3];
    out4[tb + fi] = s4;
    if (t < T - 1) {                         // t=4's mem is never read
      float4 nm; nm.x = mv[0]; nm.y = mv[1]; nm.z = mv[2]; nm.w = mv[3];
      memb[fi] = nm;
    }
  }

  if (t < T - 1) { // partials[4] never read
#pragma unroll
    for (int off = 32; off > 0; off >>= 1) local += __shfl_down(local, off);
    __shared__ unsigned int wsum[STHREADS / 64];
    if ((tid & 63) == 0) wsum[tid >> 6] = local;
    __syncthreads();
    if (tid == 0)
      partials[t * SBLOCKS + blk] = wsum[0] + wsum[1] + wsum[2] + wsum[3];
  }
}

// ---- fallback: R7's passing redundant-pair kernel (used only if ws too small)
constexpr int FTHREADS = 1024;
constexpr int FWAVES   = FTHREADS / 64;
constexpr int FBLOCKS  = 2 * C;
constexpr int FK       = 8;

__global__ __launch_bounds__(FTHREADS)
void lif_fallback(const float* __restrict__ xe_g, const float* __restrict__ xi_g,
                  const float* __restrict__ alpha_raw,
                  const float* __restrict__ beta_raw, float* __restrict__ out) {
#pragma clang fp contract(off)
  const int blk = blockIdx.x, c = blk & (C - 1), half = blk >> 7;
  const int tid = threadIdx.x, wave = tid >> 6, lane = tid & 63;
  __shared__ unsigned int wsum[T - 1][FWAVES];
  const float alpha = 4.0f / (1.0f + expf(-alpha_raw[0]));
  const float beta  = 1.0f / (1.0f + expf(-beta_raw[0]));
  float mem[FK][4];
#pragma unroll
  for (int k = 0; k < FK; ++k)
#pragma unroll
    for (int j = 0; j < 4; ++j) mem[k][j] = 0.0f;
  float ema = 0.17f, inhw = 0.0f;
  const float4* xe4 = (const float4*)xe_g;
  const float4* xi4 = (const float4*)xi_g;
  float4* o4 = (float4*)out;
  auto gidx = [&](int t, int k) -> size_t {
    const int b = k * (FTHREADS / 256) + (tid >> 8);
    return (size_t)t * NPT4 + (size_t)(b * C + c) * 256 + (tid & 255);
  };
  for (int t = 0; t < T; ++t) {
    float4 e4[FK], i4[FK];
#pragma unroll
    for (int k = 0; k < FK; ++k) { const size_t idx = gidx(t, k); e4[k] = xe4[idx]; i4[k] = xi4[idx]; }
    unsigned int local = 0;
#pragma unroll
    for (int k = 0; k < FK; ++k) {
      const float xe[4] = {e4[k].x, e4[k].y, e4[k].z, e4[k].w};
      const float xi[4] = {i4[k].x, i4[k].y, i4[k].z, i4[k].w};
      float sv[4];
#pragma unroll
      for (int j = 0; j < 4; ++j) {
        const float e_in = xe[j] / (1.0f + alpha * xi[j]);
        const float a = 0.5f * mem[k][j];
        const float bb = a + e_in;
        const float d = (beta * xi[j]) * (1.0f - inhw);
        const float m = bb - d;
        const float x = m - 0.5f;
        const float s = (x >= 0.0f) ? 1.0f : 0.0f;
        local += (x >= 0.0f) ? 1u : 0u;
        mem[k][j] = m - 0.5f * s;
        sv[j] = s;
      }
      if ((k >> 2) == half) {
        float4 s4; s4.x = sv[0]; s4.y = sv[1]; s4.z = sv[2]; s4.w = sv[3];
        o4[gidx(t, k)] = s4;
      }
    }
    if (t == T - 1) break;
#pragma unroll
    for (int off = 32; off > 0; off >>= 1) local += __shfl_down(local, off);
    if (lane == 0) wsum[t][wave] = local;
    __syncthreads();
    unsigned int total = 0;
#pragma unroll
    for (int w = 0; w < FWAVES; ++w) total += wsum[t][w];
    const float mean_spike = (float)total * (1.0f / 32768.0f);
    ema = 0.9f * ema + 0.1f * mean_spike;
    const float s_lo = 1.0f / (1.0f + expf(-(0.17f - ema)));
    const float s_hi = 1.0f / (1.0f + expf(-(ema - 0.23f)));
    inhw = 4.0f * (s_lo - s_hi);
  }
}

extern "C" void kernel_launch(void* const* d_in, const int* in_sizes, int n_in,
                              void* d_out, int out_size, void* d_ws, size_t ws_size,
                              hipStream_t stream) {
  const float* xe = (const float*)d_in[0];
  const float* xi = (const float*)d_in[1];
  const float* ar = (const float*)d_in[2];
  const float* br = (const float*)d_in[3];
  float* out = (float*)d_out;

  if (ws_size >= WS_NEEDED) {
    unsigned int* partials = (unsigned int*)d_ws;
    float4* memb = (float4*)((char*)d_ws + PART_BYTES);
    const float4* xe4 = (const float4*)xe;
    const float4* xi4 = (const float4*)xi;
    float4* out4 = (float4*)out;
    for (int t = 0; t < T; ++t)
      lif_step<<<dim3(SBLOCKS), dim3(STHREADS), 0, stream>>>(
          xe4, xi4, ar, br, out4, memb, partials, t);
  } else {
    // deterministic fallback (ws_size is constant per session -> same path
    // every call, graph-capture safe): R7's passing kernel, ~114us
    lif_fallback<<<dim3(FBLOCKS), dim3(FTHREADS), 0, stream>>>(xe, xi, ar, br, out);
  }
}